// Round 6
// baseline (482.554 us; speedup 1.0000x reference)
//
#include <hip/hip_runtime.h>
#include <hip/hip_cooperative_groups.h>
namespace cg = cooperative_groups;

#define NN 2048
#define WW 32            // u64 words per bitmask row
#define DD 512
#define MS 512           // super nodes
#define TGTM 1536        // merges = NN - MS
#define KEYMAX 0x3FFFFFu
#define CB 128           // cooperative blocks
#define CT 1024          // cooperative threads/block
#define ASL 64           // coarseA members per slice
#define NSL 25           // 25*64=1600 >= max cluster size 1537

typedef unsigned long long ull;

__device__ __forceinline__ void atomicMin64(ull* p, ull v){
  ull old = *p;
  while (v < old){
    ull assumed = old;
    old = atomicCAS(p, assumed, v);
    if (old == assumed) break;
  }
}

// Build 2048-bit adjacency bitmasks, degrees (wave-reduced), comp init.
__global__ void k_build_bits(const float* __restrict__ A, ull* __restrict__ bits,
                             unsigned* __restrict__ deg, unsigned* __restrict__ comp){
  int gid = blockIdx.x*blockDim.x + threadIdx.x;   // NN*WW threads
  int i = gid >> 5, w = gid & 31;
  const float4* row = (const float4*)(A + ((size_t)i << 11) + (w << 6));
  ull m = 0ull;
  #pragma unroll
  for (int k = 0; k < 16; ++k){
    float4 v = row[k];
    if (v.x > 0.0f) m |= (1ull << (4*k+0));
    if (v.y > 0.0f) m |= (1ull << (4*k+1));
    if (v.z > 0.0f) m |= (1ull << (4*k+2));
    if (v.w > 0.0f) m |= (1ull << (4*k+3));
  }
  bits[((size_t)i << 5) + w] = m;
  unsigned p = (unsigned)__popcll(m);
  for (int off = 16; off; off >>= 1) p += __shfl_xor(p, off, 32);
  if (w == 0) deg[i] = p;
  if (gid < NN) comp[gid] = (unsigned)gid;
}

// Full symmetric key matrix: key22 = round(inter * 2^22 / union), exact int math.
__global__ void k_keymat(const ull* __restrict__ bits,
                         const unsigned* __restrict__ deg, unsigned* __restrict__ keyM){
  __shared__ ull bi[64][33];
  __shared__ ull bj[64][33];
  __shared__ unsigned degi[64], degj[64];
  int ib = blockIdx.x, jb = blockIdx.y;
  int t = threadIdx.x;
  for (int idx = t; idx < 64*32; idx += 256){
    int r = idx >> 5, w = idx & 31;
    bi[r][w] = bits[(((size_t)(ib*64 + r)) << 5) + w];
    bj[r][w] = bits[(((size_t)(jb*64 + r)) << 5) + w];
  }
  if (t < 64){ degi[t] = deg[ib*64 + t]; degj[t] = deg[jb*64 + t]; }
  __syncthreads();
  for (int p = t; p < 4096; p += 256){
    int ii = p >> 6, jj = p & 63;
    int i = ib*64 + ii, j = jb*64 + jj;
    unsigned key = 0u;
    if (i != j){
      unsigned inter = 0;
      #pragma unroll
      for (int w = 0; w < 32; ++w) inter += (unsigned)__popcll(bi[ii][w] & bj[jj][w]);
      unsigned b = degi[ii] + degj[jj] - inter;
      if (b != 0u){
        ull num = (((ull)inter) << 22) + (b >> 1);
        ull q = num / b;
        key = (q > (ull)KEYMAX) ? KEYMAX : (unsigned)q;
      }
    }
    keyM[((size_t)i << 11) + j] = key;
  }
}

// Fused Boruvka (all rounds) + finalization, one cooperative kernel.
// 128 blocks x 1024 threads = 2048 waves; wave g owns node g in the best phase.
// Block 0 runs the merge phase and, after the loop, the final phase.
__global__ void __launch_bounds__(CT)
k_boruvka(const unsigned* __restrict__ keyM, unsigned* __restrict__ comp,
          ull* __restrict__ node_best, unsigned* __restrict__ msf_cnt,
          unsigned* __restrict__ labels_g, float* __restrict__ scale_g,
          unsigned* __restrict__ offs_g, unsigned* __restrict__ memb_g,
          float* __restrict__ P){
  cg::grid_group grid = cg::this_grid();
  __shared__ ull ed[NN];       // block0: collected MSF edges, later sort buffer / fo / plab
  __shared__ ull cbest[NN];    // block0: per-component best, later sizes/scanT
  __shared__ unsigned lab[NN]; // all blocks: comp cache (best phase); block0: labels (final)
  __shared__ unsigned nxtA[NN], nxtB[NN];
  __shared__ int flagS;
  __shared__ unsigned cntS;
  int t = threadIdx.x;
  int b = blockIdx.x;
  if (b == 0 && t == 0) cntS = 0;

  for (int round = 0; round < 11; ++round){
    // stage comp into LDS (all blocks)
    for (int i = t; i < NN; i += CT) lab[i] = comp[i];
    __syncthreads();
    // ---- best phase: wave g handles node g ----
    {
      int i = (b*CT + t) >> 6;       // 0..2047
      int lane = t & 63;
      unsigned ci = lab[i];
      const unsigned* row = keyM + ((size_t)i << 11);
      ull best = ~0ull;
      for (int j = lane; j < NN; j += 64){
        if (j == i || lab[j] == ci) continue;
        unsigned kp = KEYMAX - row[j];
        unsigned a  = (i < j) ? (unsigned)i : (unsigned)j;
        unsigned b2 = (i < j) ? (unsigned)j : (unsigned)i;
        ull v = (((ull)kp) << 22) | (((ull)a) << 11) | b2;
        if (v < best) best = v;
      }
      for (int off = 32; off; off >>= 1){
        ull o = __shfl_xor(best, off);
        if (o < best) best = o;
      }
      if (lane == 0) node_best[i] = best;
    }
    grid.sync();
    // ---- merge phase: block 0 only ----
    if (b == 0){
      for (int c = t; c < NN; c += CT) cbest[c] = ~0ull;
      __syncthreads();
      for (int i = t; i < NN; i += CT) atomicMin64(&cbest[lab[i]], node_best[i]);
      __syncthreads();
      for (int c = t; c < NN; c += CT){
        unsigned nx = (unsigned)c;
        ull v = cbest[c];
        if (v != ~0ull){
          unsigned a = (unsigned)((v >> 11) & 2047u), b2 = (unsigned)(v & 2047u);
          unsigned la = lab[a], lb = lab[b2];
          if (la != lb) nx = (la == (unsigned)c) ? lb : la;
        }
        nxtA[c] = nx;
      }
      __syncthreads();
      for (int c = t; c < NN; c += CT){
        unsigned o = nxtA[c];
        if (o != (unsigned)c && nxtA[o] == (unsigned)c && (unsigned)c < o) nxtA[c] = (unsigned)c;
      }
      __syncthreads();
      for (int c = t; c < NN; c += CT){
        if (nxtA[c] != (unsigned)c){
          unsigned idx = atomicAdd(&cntS, 1u);
          if (idx < (unsigned)NN) ed[idx] = cbest[c];
        }
      }
      __syncthreads();
      unsigned* s1 = nxtA; unsigned* s2 = nxtB;
      for (int r = 0; r < 11; ++r){
        if (t == 0) flagS = 0;
        __syncthreads();
        int ch = 0;
        for (int c = t; c < NN; c += CT){ unsigned p = s1[c], g = s1[p]; s2[c] = g; ch |= (g != p); }
        if (ch) flagS = 1;
        __syncthreads();
        unsigned* tmp = s1; s1 = s2; s2 = tmp;
        int f = flagS;
        __syncthreads();
        if (!f) break;
      }
      for (int i = t; i < NN; i += CT) comp[i] = s1[lab[i]];
      if (t == 0) *msf_cnt = cntS;
      __threadfence();
    }
    grid.sync();
    unsigned mc = *(volatile unsigned*)msf_cnt;   // uniform across grid after sync
    if (mc >= (unsigned)(NN-1)) break;
  }
  if (b != 0) return;

  // ================= final phase (block 0, 1024 threads) =================
  unsigned cnt = cntS; if (cnt > (unsigned)NN) cnt = NN;
  for (int i = t; i < NN; i += CT) if (i >= (int)cnt) ed[i] = ~0ull;
  __syncthreads();
  // bitonic sort ascending (44-bit vals unique; pads sort last)
  for (unsigned k = 2; k <= (unsigned)NN; k <<= 1)
    for (unsigned j = k >> 1; j > 0; j >>= 1){
      for (int i = t; i < NN; i += CT){
        unsigned l = ((unsigned)i) ^ j;
        if (l > (unsigned)i){
          bool up = ((((unsigned)i) & k) == 0u);
          ull x = ed[i], y = ed[l];
          if ((x > y) == up){ ed[i] = y; ed[l] = x; }
        }
      }
      __syncthreads();
    }
  // CC of first TGTM edges, hooking rounds with convergence early-exit
  for (int i = t; i < NN; i += CT) lab[i] = (unsigned)i;
  __syncthreads();
  for (int round = 0; round < 11; ++round){
    if (t == 0) flagS = 0;
    for (int c = t; c < NN; c += CT) cbest[c] = ~0ull;
    __syncthreads();
    for (int e = t; e < TGTM; e += CT){
      ull v = ed[e];
      unsigned a = (unsigned)((v >> 11) & 2047u), b2 = (unsigned)(v & 2047u);
      unsigned la = lab[a], lb = lab[b2];
      if (la != lb){ atomicMin64(&cbest[la], v); atomicMin64(&cbest[lb], v); flagS = 1; }
    }
    __syncthreads();
    int active = flagS;
    __syncthreads();
    if (!active) break;
    for (int c = t; c < NN; c += CT){
      unsigned nx = (unsigned)c;
      ull v = cbest[c];
      if (v != ~0ull){
        unsigned a = (unsigned)((v >> 11) & 2047u), b2 = (unsigned)(v & 2047u);
        unsigned la = lab[a], lb = lab[b2];
        if (la != lb) nx = (la == (unsigned)c) ? lb : la;
      }
      nxtA[c] = nx;
    }
    __syncthreads();
    for (int c = t; c < NN; c += CT){
      unsigned o = nxtA[c];
      if (o != (unsigned)c && nxtA[o] == (unsigned)c && (unsigned)c < o) nxtA[c] = (unsigned)c;
    }
    __syncthreads();
    unsigned* s1 = nxtA; unsigned* s2 = nxtB;
    for (int r = 0; r < 11; ++r){
      if (t == 0) flagS = 0;
      __syncthreads();
      int ch = 0;
      for (int c = t; c < NN; c += CT){ unsigned p = s1[c], g = s1[p]; s2[c] = g; ch |= (g != p); }
      if (ch) flagS = 1;
      __syncthreads();
      unsigned* tmp = s1; s1 = s2; s2 = tmp;
      int f = flagS;
      __syncthreads();
      if (!f) break;
    }
    for (int i = t; i < NN; i += CT) lab[i] = s1[lab[i]];
    __syncthreads();
  }
  // labels = rank of class by min member; sizes; scale; member lists; P
  unsigned* fo    = (unsigned*)ed;
  unsigned* plab  = ((unsigned*)ed) + NN;
  unsigned* sizes = (unsigned*)cbest;          // [0,512)
  unsigned* scanT = ((unsigned*)cbest) + 1024; // 1024 entries
  for (int i = t; i < NN; i += CT) fo[i] = 0xFFFFFFFFu;
  __syncthreads();
  for (int i = t; i < NN; i += CT) atomicMin(&fo[lab[i]], (unsigned)i);
  __syncthreads();
  int i0 = 2*t, i1 = 2*t + 1;
  unsigned f0 = (fo[lab[i0]] == (unsigned)i0) ? 1u : 0u;
  unsigned f1 = (fo[lab[i1]] == (unsigned)i1) ? 1u : 0u;
  unsigned s = f0 + f1;
  scanT[t] = s; __syncthreads();
  for (int off = 1; off < CT; off <<= 1){
    unsigned x = (t >= off) ? scanT[t-off] : 0u;
    __syncthreads();
    scanT[t] += x;
    __syncthreads();
  }
  unsigned excl = scanT[t] - s;
  plab[i0] = excl; plab[i1] = excl + f0;
  __syncthreads();
  for (int c = t; c < MS; c += CT) sizes[c] = 0u;
  __syncthreads();
  for (int i = t; i < NN; i += CT){
    unsigned L = plab[fo[lab[i]]];
    labels_g[i] = L;
    if (L < (unsigned)MS) atomicAdd(&sizes[L], 1u);
  }
  __syncthreads();
  for (int c = t; c < MS; c += CT) scale_g[c] = 1.0f / sqrtf((float)sizes[c] + 1e-10f);
  // offs: exclusive scan of sizes
  unsigned* off_l  = nxtA;
  unsigned* cursor = nxtA + 1024;
  unsigned my = (t < MS) ? sizes[t] : 0u;
  scanT[t] = my; __syncthreads();
  for (int off = 1; off < CT; off <<= 1){
    unsigned x = (t >= off) ? scanT[t-off] : 0u;
    __syncthreads();
    scanT[t] += x;
    __syncthreads();
  }
  if (t < MS){
    unsigned ex = scanT[t] - my;
    off_l[t] = ex; offs_g[t] = ex;
  }
  if (t == 0) offs_g[MS] = (unsigned)NN;
  __syncthreads();
  for (int c = t; c < MS; c += CT) cursor[c] = off_l[c];
  __syncthreads();
  for (int i = t; i < NN; i += CT){
    unsigned L = plab[fo[lab[i]]];
    unsigned pos = atomicAdd(&cursor[L], 1u);
    memb_g[pos] = (unsigned)i;
  }
  for (int i = t; i < NN; i += CT){
    unsigned L = plab[fo[lab[i]]];
    P[((size_t)i << 9) + L] = 1.0f / sqrtf((float)sizes[L] + 1e-10f);
  }
}

// X_coarse: grid (cluster, d-tile of 128), 128 threads; LDS member list, 8-deep ILP.
__global__ void k_coarseX(const float* __restrict__ X, const unsigned* __restrict__ offs,
                          const unsigned* __restrict__ memb, const float* __restrict__ scale,
                          float* __restrict__ Xc){
  __shared__ unsigned mlist[NN];
  int c = blockIdx.x;
  int d = blockIdx.y*128 + threadIdx.x;
  unsigned o = offs[c], e = offs[c+1];
  int nm = (int)(e - o);
  for (int k = threadIdx.x; k < nm; k += 128) mlist[k] = memb[o + k];
  __syncthreads();
  float a0=0.f,a1=0.f,a2=0.f,a3=0.f,a4=0.f,a5=0.f,a6=0.f,a7=0.f;
  int k = 0;
  for (; k + 8 <= nm; k += 8){
    a0 += X[((size_t)mlist[k+0] << 9) + d];
    a1 += X[((size_t)mlist[k+1] << 9) + d];
    a2 += X[((size_t)mlist[k+2] << 9) + d];
    a3 += X[((size_t)mlist[k+3] << 9) + d];
    a4 += X[((size_t)mlist[k+4] << 9) + d];
    a5 += X[((size_t)mlist[k+5] << 9) + d];
    a6 += X[((size_t)mlist[k+6] << 9) + d];
    a7 += X[((size_t)mlist[k+7] << 9) + d];
  }
  for (; k < nm; ++k) a0 += X[((size_t)mlist[k] << 9) + d];
  float acc = ((a0+a1)+(a2+a3)) + ((a4+a5)+(a6+a7));
  Xc[((size_t)c << 9) + d] = acc * scale[c];
}

// A_coarse: grid (cluster, slice of <=64 members), LDS histogram per slice.
// Single-slice clusters store the full row; multi-slice clusters atomicAdd
// nonzeros onto the pre-zeroed Ac. Worst block: 8 strided iterations.
__global__ void k_coarseA(const ull* __restrict__ bits,
                          const unsigned* __restrict__ labels,
                          const unsigned* __restrict__ offs, const unsigned* __restrict__ memb,
                          const float* __restrict__ scale, float* __restrict__ Ac){
  __shared__ float row[MS];
  __shared__ unsigned labS[NN];
  __shared__ unsigned mlist[ASL];
  int c = blockIdx.x, sl = blockIdx.y, t = threadIdx.x;
  unsigned o0 = offs[c], e = offs[c+1];
  unsigned o = o0 + (unsigned)sl*ASL;
  if (o >= e) return;                       // uniform per block
  int nm = (int)min((unsigned)ASL, e - o);
  for (int j = t; j < MS; j += 256) row[j] = 0.0f;
  for (int i = t; i < NN; i += 256) labS[i] = labels[i];
  if (t < nm) mlist[t] = memb[o + t];
  __syncthreads();
  for (int idx = t; idx < nm*WW; idx += 256){
    unsigned m = mlist[idx >> 5];
    int w = idx & 31;
    ull word = bits[((size_t)m << 5) + w];
    while (word){
      int bb = __ffsll((long long)word) - 1;
      unsigned j = (unsigned)(w*64 + bb);
      atomicAdd(&row[labS[j]], 1.0f);       // LDS atomic
      word &= word - 1ull;
    }
  }
  __syncthreads();
  float sc = scale[c];
  bool single = (e - o0) <= (unsigned)ASL;
  if (single){
    for (int j = t; j < MS; j += 256)
      Ac[((size_t)c << 9) + j] = row[j] * sc * scale[j];
  } else {
    for (int j = t; j < MS; j += 256){
      float v = row[j];
      if (v != 0.0f) atomicAdd(&Ac[((size_t)c << 9) + j], v * sc * scale[j]);
    }
  }
}

extern "C" void kernel_launch(void* const* d_in, const int* in_sizes, int n_in,
                              void* d_out, int out_size, void* d_ws, size_t ws_size,
                              hipStream_t stream) {
  const float* X = (const float*)d_in[0];
  const float* A = (const float*)d_in[1];
  float* out = (float*)d_out;
  char* ws = (char*)d_ws;
  ull*      bits     = (ull*)     (ws + 0x000000);  // 512 KB, live whole run
  unsigned* deg      = (unsigned*)(ws + 0x080000);  // 8 KB (dead after keymat)
  unsigned* comp     = (unsigned*)(ws + 0x082000);  // 8 KB
  ull*      nodebest = (ull*)     (ws + 0x084000);  // 16 KB (dead after boruvka)
  unsigned* msfcnt   = (unsigned*)(ws + 0x08C000);  // 4 B
  unsigned* labels   = (unsigned*)(ws + 0x08D000);  // 8 KB
  float*    scale    = (float*)   (ws + 0x08F000);  // 2 KB
  unsigned* memb     = (unsigned*)(ws + 0x084000);  // overlays nodebest (8 KB)
  unsigned* offs     = (unsigned*)(ws + 0x080000);  // overlays deg (2052 B)
  unsigned* keyM     = (unsigned*)(ws + 0x090000);  // 16 MB

  float* Xc = out;
  float* Ac = out + MS*MS;
  float* P  = out + 2*MS*MS;

  hipMemsetAsync(P,  0, (size_t)NN*MS*sizeof(float), stream);   // P region (4 MB)
  hipMemsetAsync(Ac, 0, (size_t)MS*MS*sizeof(float), stream);   // Ac region (1 MB)

  k_build_bits<<<(NN*WW)/256, 256, 0, stream>>>(A, bits, deg, comp);
  k_keymat<<<dim3(NN/64, NN/64), 256, 0, stream>>>(bits, deg, keyM);

  void* args[] = { (void*)&keyM, (void*)&comp, (void*)&nodebest, (void*)&msfcnt,
                   (void*)&labels, (void*)&scale, (void*)&offs, (void*)&memb, (void*)&P };
  hipLaunchCooperativeKernel((void*)k_boruvka, dim3(CB), dim3(CT), args, 0, stream);

  k_coarseX<<<dim3(MS, DD/128), 128, 0, stream>>>(X, offs, memb, scale, Xc);
  k_coarseA<<<dim3(MS, NSL), 256, 0, stream>>>(bits, labels, offs, memb, scale, Ac);
}

// Round 7
// 415.666 us; speedup vs baseline: 1.1609x; 1.1609x over previous
//
#include <hip/hip_runtime.h>
#include <hip/hip_cooperative_groups.h>
namespace cg = cooperative_groups;

#define NN 2048
#define WW 32            // u64 words per bitmask row
#define DD 512
#define MS 512           // super nodes
#define TGTM 1536        // merges = NN - MS
#define KEYMAX 0x3FFFFFu
#define CB 64            // cooperative blocks
#define CT 1024          // cooperative threads/block
#define ASL 64           // coarseA members per slice
#define NSL 25           // 25*64=1600 >= max cluster size 1537

typedef unsigned long long ull;

__device__ __forceinline__ void atomicMin64(ull* p, ull v){
  ull old = *p;
  while (v < old){
    ull assumed = old;
    old = atomicCAS(p, assumed, v);
    if (old == assumed) break;
  }
}

// Build 2048-bit adjacency bitmasks + degrees (wave-reduced).
__global__ void k_build_bits(const float* __restrict__ A, ull* __restrict__ bits,
                             unsigned* __restrict__ deg){
  int gid = blockIdx.x*blockDim.x + threadIdx.x;   // NN*WW threads
  int i = gid >> 5, w = gid & 31;
  const float4* row = (const float4*)(A + ((size_t)i << 11) + (w << 6));
  ull m = 0ull;
  #pragma unroll
  for (int k = 0; k < 16; ++k){
    float4 v = row[k];
    if (v.x > 0.0f) m |= (1ull << (4*k+0));
    if (v.y > 0.0f) m |= (1ull << (4*k+1));
    if (v.z > 0.0f) m |= (1ull << (4*k+2));
    if (v.w > 0.0f) m |= (1ull << (4*k+3));
  }
  bits[((size_t)i << 5) + w] = m;
  unsigned p = (unsigned)__popcll(m);
  for (int off = 16; off; off >>= 1) p += __shfl_xor(p, off, 32);
  if (w == 0) deg[i] = p;
}

// Full symmetric key matrix: key22 = round(inter * 2^22 / union), exact int math.
__global__ void k_keymat(const ull* __restrict__ bits,
                         const unsigned* __restrict__ deg, unsigned* __restrict__ keyM){
  __shared__ ull bi[64][33];
  __shared__ ull bj[64][33];
  __shared__ unsigned degi[64], degj[64];
  int ib = blockIdx.x, jb = blockIdx.y;
  int t = threadIdx.x;
  for (int idx = t; idx < 64*32; idx += 256){
    int r = idx >> 5, w = idx & 31;
    bi[r][w] = bits[(((size_t)(ib*64 + r)) << 5) + w];
    bj[r][w] = bits[(((size_t)(jb*64 + r)) << 5) + w];
  }
  if (t < 64){ degi[t] = deg[ib*64 + t]; degj[t] = deg[jb*64 + t]; }
  __syncthreads();
  for (int p = t; p < 4096; p += 256){
    int ii = p >> 6, jj = p & 63;
    int i = ib*64 + ii, j = jb*64 + jj;
    unsigned key = 0u;
    if (i != j){
      unsigned inter = 0;
      #pragma unroll
      for (int w = 0; w < 32; ++w) inter += (unsigned)__popcll(bi[ii][w] & bj[jj][w]);
      unsigned b = degi[ii] + degj[jj] - inter;
      if (b != 0u){
        ull num = (((ull)inter) << 22) + (b >> 1);
        ull q = num / b;
        key = (q > (ull)KEYMAX) ? KEYMAX : (unsigned)q;
      }
    }
    keyM[((size_t)i << 11) + j] = key;
  }
}

// Fused Boruvka + finalization, ONE grid.sync per round.
// Every block keeps its own comp copy (lab) in LDS and redundantly executes
// the identical merge (LDS-atomicMin result is order-independent -> all blocks
// stay bit-identical). Only node_best crosses blocks, double-buffered by
// round parity so the single sync suffices (no write-after-read race).
__global__ void __launch_bounds__(CT)
k_boruvka(const unsigned* __restrict__ keyM, ull* __restrict__ node_best /*[2][NN]*/,
          unsigned* __restrict__ labels_g, float* __restrict__ scale_g,
          unsigned* __restrict__ offs_g, unsigned* __restrict__ memb_g,
          float* __restrict__ P){
  cg::grid_group grid = cg::this_grid();
  __shared__ ull ed[NN];       // collected MSF edges; later sort buffer / fo / plab
  __shared__ ull cbest[NN];    // per-component best; later sizes/scanT
  __shared__ unsigned lab[NN]; // per-block comp copy; later CC labels
  __shared__ unsigned nxtA[NN], nxtB[NN];
  __shared__ int flagS;
  __shared__ unsigned cntS;
  int t = threadIdx.x;
  int b = blockIdx.x;
  if (t == 0) cntS = 0;
  for (int i = t; i < NN; i += CT) lab[i] = (unsigned)i;
  __syncthreads();

  for (int round = 0; round < 11; ++round){
    ull* nb = node_best + ((round & 1) ? NN : 0);
    // ---- best phase: this block's 32 rows, 2 per wave ----
    {
      int wv = b*(CT/64) + (t >> 6);     // global wave id 0..1023
      int lane = t & 63;
      #pragma unroll
      for (int rr = 0; rr < 2; ++rr){
        int i = wv*2 + rr;
        unsigned ci = lab[i];
        const unsigned* row = keyM + ((size_t)i << 11);
        ull best = ~0ull;
        for (int j = lane; j < NN; j += 64){
          if (j == i || lab[j] == ci) continue;
          unsigned kp = KEYMAX - row[j];
          unsigned a  = (i < j) ? (unsigned)i : (unsigned)j;
          unsigned b2 = (i < j) ? (unsigned)j : (unsigned)i;
          ull v = (((ull)kp) << 22) | (((ull)a) << 11) | b2;
          if (v < best) best = v;
        }
        for (int off = 32; off; off >>= 1){
          ull o = __shfl_xor(best, off);
          if (o < best) best = o;
        }
        if (lane == 0) nb[i] = best;
      }
    }
    grid.sync();
    // ---- merge phase: ALL blocks, redundant & identical ----
    for (int c = t; c < NN; c += CT) cbest[c] = ~0ull;
    __syncthreads();
    for (int i = t; i < NN; i += CT) atomicMin64(&cbest[lab[i]], nb[i]);
    __syncthreads();
    for (int c = t; c < NN; c += CT){
      unsigned nx = (unsigned)c;
      ull v = cbest[c];
      if (v != ~0ull){
        unsigned a = (unsigned)((v >> 11) & 2047u), b2 = (unsigned)(v & 2047u);
        unsigned la = lab[a], lb = lab[b2];
        if (la != lb) nx = (la == (unsigned)c) ? lb : la;
      }
      nxtA[c] = nx;
    }
    __syncthreads();
    for (int c = t; c < NN; c += CT){
      unsigned o = nxtA[c];
      if (o != (unsigned)c && nxtA[o] == (unsigned)c && (unsigned)c < o) nxtA[c] = (unsigned)c;
    }
    __syncthreads();
    for (int c = t; c < NN; c += CT){
      if (nxtA[c] != (unsigned)c){
        unsigned idx = atomicAdd(&cntS, 1u);
        if (idx < (unsigned)NN) ed[idx] = cbest[c];
      }
    }
    __syncthreads();
    unsigned* s1 = nxtA; unsigned* s2 = nxtB;
    for (int r = 0; r < 11; ++r){
      if (t == 0) flagS = 0;
      __syncthreads();
      int ch = 0;
      for (int c = t; c < NN; c += CT){ unsigned p = s1[c], g = s1[p]; s2[c] = g; ch |= (g != p); }
      if (ch) flagS = 1;
      __syncthreads();
      unsigned* tmp = s1; s1 = s2; s2 = tmp;
      int f = flagS;
      __syncthreads();
      if (!f) break;
    }
    for (int i = t; i < NN; i += CT) lab[i] = s1[lab[i]];
    __syncthreads();
    if (cntS >= (unsigned)(NN-1)) break;   // identical in every block
  }
  if (b != 0) return;

  // ================= final phase (block 0 only) =================
  unsigned cnt = cntS; if (cnt > (unsigned)NN) cnt = NN;
  for (int i = t; i < NN; i += CT) if (i >= (int)cnt) ed[i] = ~0ull;
  __syncthreads();
  // bitonic sort ascending (44-bit vals unique; pads sort last)
  for (unsigned k = 2; k <= (unsigned)NN; k <<= 1)
    for (unsigned j = k >> 1; j > 0; j >>= 1){
      for (int i = t; i < NN; i += CT){
        unsigned l = ((unsigned)i) ^ j;
        if (l > (unsigned)i){
          bool up = ((((unsigned)i) & k) == 0u);
          ull x = ed[i], y = ed[l];
          if ((x > y) == up){ ed[i] = y; ed[l] = x; }
        }
      }
      __syncthreads();
    }
  // CC of first TGTM edges, hooking rounds with convergence early-exit
  for (int i = t; i < NN; i += CT) lab[i] = (unsigned)i;
  __syncthreads();
  for (int round = 0; round < 11; ++round){
    if (t == 0) flagS = 0;
    for (int c = t; c < NN; c += CT) cbest[c] = ~0ull;
    __syncthreads();
    for (int e = t; e < TGTM; e += CT){
      ull v = ed[e];
      unsigned a = (unsigned)((v >> 11) & 2047u), b2 = (unsigned)(v & 2047u);
      unsigned la = lab[a], lb = lab[b2];
      if (la != lb){ atomicMin64(&cbest[la], v); atomicMin64(&cbest[lb], v); flagS = 1; }
    }
    __syncthreads();
    int active = flagS;
    __syncthreads();
    if (!active) break;
    for (int c = t; c < NN; c += CT){
      unsigned nx = (unsigned)c;
      ull v = cbest[c];
      if (v != ~0ull){
        unsigned a = (unsigned)((v >> 11) & 2047u), b2 = (unsigned)(v & 2047u);
        unsigned la = lab[a], lb = lab[b2];
        if (la != lb) nx = (la == (unsigned)c) ? lb : la;
      }
      nxtA[c] = nx;
    }
    __syncthreads();
    for (int c = t; c < NN; c += CT){
      unsigned o = nxtA[c];
      if (o != (unsigned)c && nxtA[o] == (unsigned)c && (unsigned)c < o) nxtA[c] = (unsigned)c;
    }
    __syncthreads();
    unsigned* s1 = nxtA; unsigned* s2 = nxtB;
    for (int r = 0; r < 11; ++r){
      if (t == 0) flagS = 0;
      __syncthreads();
      int ch = 0;
      for (int c = t; c < NN; c += CT){ unsigned p = s1[c], g = s1[p]; s2[c] = g; ch |= (g != p); }
      if (ch) flagS = 1;
      __syncthreads();
      unsigned* tmp = s1; s1 = s2; s2 = tmp;
      int f = flagS;
      __syncthreads();
      if (!f) break;
    }
    for (int i = t; i < NN; i += CT) lab[i] = s1[lab[i]];
    __syncthreads();
  }
  // labels = rank of class by min member; sizes; scale; member lists; P
  unsigned* fo    = (unsigned*)ed;
  unsigned* plab  = ((unsigned*)ed) + NN;
  unsigned* sizes = (unsigned*)cbest;          // [0,512)
  unsigned* scanT = ((unsigned*)cbest) + 1024; // 1024 entries
  for (int i = t; i < NN; i += CT) fo[i] = 0xFFFFFFFFu;
  __syncthreads();
  for (int i = t; i < NN; i += CT) atomicMin(&fo[lab[i]], (unsigned)i);
  __syncthreads();
  int i0 = 2*t, i1 = 2*t + 1;
  unsigned f0 = (fo[lab[i0]] == (unsigned)i0) ? 1u : 0u;
  unsigned f1 = (fo[lab[i1]] == (unsigned)i1) ? 1u : 0u;
  unsigned s = f0 + f1;
  scanT[t] = s; __syncthreads();
  for (int off = 1; off < CT; off <<= 1){
    unsigned x = (t >= off) ? scanT[t-off] : 0u;
    __syncthreads();
    scanT[t] += x;
    __syncthreads();
  }
  unsigned excl = scanT[t] - s;
  plab[i0] = excl; plab[i1] = excl + f0;
  __syncthreads();
  for (int c = t; c < MS; c += CT) sizes[c] = 0u;
  __syncthreads();
  for (int i = t; i < NN; i += CT){
    unsigned L = plab[fo[lab[i]]];
    labels_g[i] = L;
    if (L < (unsigned)MS) atomicAdd(&sizes[L], 1u);
  }
  __syncthreads();
  for (int c = t; c < MS; c += CT) scale_g[c] = 1.0f / sqrtf((float)sizes[c] + 1e-10f);
  // offs: exclusive scan of sizes
  unsigned* off_l  = nxtA;
  unsigned* cursor = nxtA + 1024;
  unsigned my = (t < MS) ? sizes[t] : 0u;
  scanT[t] = my; __syncthreads();
  for (int off = 1; off < CT; off <<= 1){
    unsigned x = (t >= off) ? scanT[t-off] : 0u;
    __syncthreads();
    scanT[t] += x;
    __syncthreads();
  }
  if (t < MS){
    unsigned ex = scanT[t] - my;
    off_l[t] = ex; offs_g[t] = ex;
  }
  if (t == 0) offs_g[MS] = (unsigned)NN;
  __syncthreads();
  for (int c = t; c < MS; c += CT) cursor[c] = off_l[c];
  __syncthreads();
  for (int i = t; i < NN; i += CT){
    unsigned L = plab[fo[lab[i]]];
    unsigned pos = atomicAdd(&cursor[L], 1u);
    memb_g[pos] = (unsigned)i;
  }
  for (int i = t; i < NN; i += CT){
    unsigned L = plab[fo[lab[i]]];
    P[((size_t)i << 9) + L] = 1.0f / sqrtf((float)sizes[L] + 1e-10f);
  }
}

// X_coarse: grid (cluster, d-tile of 128), 128 threads; LDS member list, 8-deep ILP.
__global__ void k_coarseX(const float* __restrict__ X, const unsigned* __restrict__ offs,
                          const unsigned* __restrict__ memb, const float* __restrict__ scale,
                          float* __restrict__ Xc){
  __shared__ unsigned mlist[NN];
  int c = blockIdx.x;
  int d = blockIdx.y*128 + threadIdx.x;
  unsigned o = offs[c], e = offs[c+1];
  int nm = (int)(e - o);
  for (int k = threadIdx.x; k < nm; k += 128) mlist[k] = memb[o + k];
  __syncthreads();
  float a0=0.f,a1=0.f,a2=0.f,a3=0.f,a4=0.f,a5=0.f,a6=0.f,a7=0.f;
  int k = 0;
  for (; k + 8 <= nm; k += 8){
    a0 += X[((size_t)mlist[k+0] << 9) + d];
    a1 += X[((size_t)mlist[k+1] << 9) + d];
    a2 += X[((size_t)mlist[k+2] << 9) + d];
    a3 += X[((size_t)mlist[k+3] << 9) + d];
    a4 += X[((size_t)mlist[k+4] << 9) + d];
    a5 += X[((size_t)mlist[k+5] << 9) + d];
    a6 += X[((size_t)mlist[k+6] << 9) + d];
    a7 += X[((size_t)mlist[k+7] << 9) + d];
  }
  for (; k < nm; ++k) a0 += X[((size_t)mlist[k] << 9) + d];
  float acc = ((a0+a1)+(a2+a3)) + ((a4+a5)+(a6+a7));
  Xc[((size_t)c << 9) + d] = acc * scale[c];
}

// A_coarse: grid (cluster, slice of <=64 members), LDS histogram per slice.
__global__ void k_coarseA(const ull* __restrict__ bits,
                          const unsigned* __restrict__ labels,
                          const unsigned* __restrict__ offs, const unsigned* __restrict__ memb,
                          const float* __restrict__ scale, float* __restrict__ Ac){
  __shared__ float row[MS];
  __shared__ unsigned labS[NN];
  __shared__ unsigned mlist[ASL];
  int c = blockIdx.x, sl = blockIdx.y, t = threadIdx.x;
  unsigned o0 = offs[c], e = offs[c+1];
  unsigned o = o0 + (unsigned)sl*ASL;
  if (o >= e) return;                       // uniform per block
  int nm = (int)min((unsigned)ASL, e - o);
  for (int j = t; j < MS; j += 256) row[j] = 0.0f;
  for (int i = t; i < NN; i += 256) labS[i] = labels[i];
  if (t < nm) mlist[t] = memb[o + t];
  __syncthreads();
  for (int idx = t; idx < nm*WW; idx += 256){
    unsigned m = mlist[idx >> 5];
    int w = idx & 31;
    ull word = bits[((size_t)m << 5) + w];
    while (word){
      int bb = __ffsll((long long)word) - 1;
      unsigned j = (unsigned)(w*64 + bb);
      atomicAdd(&row[labS[j]], 1.0f);       // LDS atomic
      word &= word - 1ull;
    }
  }
  __syncthreads();
  float sc = scale[c];
  bool single = (e - o0) <= (unsigned)ASL;
  if (single){
    for (int j = t; j < MS; j += 256)
      Ac[((size_t)c << 9) + j] = row[j] * sc * scale[j];
  } else {
    for (int j = t; j < MS; j += 256){
      float v = row[j];
      if (v != 0.0f) atomicAdd(&Ac[((size_t)c << 9) + j], v * sc * scale[j]);
    }
  }
}

extern "C" void kernel_launch(void* const* d_in, const int* in_sizes, int n_in,
                              void* d_out, int out_size, void* d_ws, size_t ws_size,
                              hipStream_t stream) {
  const float* X = (const float*)d_in[0];
  const float* A = (const float*)d_in[1];
  float* out = (float*)d_out;
  char* ws = (char*)d_ws;
  ull*      bits     = (ull*)     (ws + 0x000000);  // 512 KB, live whole run
  unsigned* deg      = (unsigned*)(ws + 0x080000);  // 8 KB (dead after keymat)
  ull*      nodebest = (ull*)     (ws + 0x084000);  // 32 KB double-buffered (dead after boruvka)
  unsigned* labels   = (unsigned*)(ws + 0x08D000);  // 8 KB
  float*    scale    = (float*)   (ws + 0x08F000);  // 2 KB
  unsigned* memb     = (unsigned*)(ws + 0x084000);  // overlays nodebest (8 KB)
  unsigned* offs     = (unsigned*)(ws + 0x080000);  // overlays deg (2052 B)
  unsigned* keyM     = (unsigned*)(ws + 0x090000);  // 16 MB

  float* Xc = out;
  float* Ac = out + MS*MS;
  float* P  = out + 2*MS*MS;

  hipMemsetAsync(P,  0, (size_t)NN*MS*sizeof(float), stream);   // P region (4 MB)
  hipMemsetAsync(Ac, 0, (size_t)MS*MS*sizeof(float), stream);   // Ac region (1 MB)

  k_build_bits<<<(NN*WW)/256, 256, 0, stream>>>(A, bits, deg);
  k_keymat<<<dim3(NN/64, NN/64), 256, 0, stream>>>(bits, deg, keyM);

  void* args[] = { (void*)&keyM, (void*)&nodebest,
                   (void*)&labels, (void*)&scale, (void*)&offs, (void*)&memb, (void*)&P };
  hipLaunchCooperativeKernel((void*)k_boruvka, dim3(CB), dim3(CT), args, 0, stream);

  k_coarseX<<<dim3(MS, DD/128), 128, 0, stream>>>(X, offs, memb, scale, Xc);
  k_coarseA<<<dim3(MS, NSL), 256, 0, stream>>>(bits, labels, offs, memb, scale, Ac);
}